// Round 7
// baseline (388.797 us; speedup 1.0000x reference)
//
#include <hip/hip_runtime.h>
#include <hip/hip_bf16.h>

typedef __hip_bfloat16 bf16;
typedef __attribute__((ext_vector_type(8))) short short8;
typedef __attribute__((ext_vector_type(4))) float f32x4;

#define SCALE_F 0.0625f   // 256^-0.5

// ---------- small helpers ----------
__device__ __forceinline__ float b2f(short s) {
  union { float f; unsigned int u; } x;
  x.u = ((unsigned int)(unsigned short)s) << 16;
  return x.f;
}
__device__ __forceinline__ unsigned short f2bu(float f) {
  __hip_bfloat16 h = __float2bfloat16(f);
  unsigned short u;
  __builtin_memcpy(&u, &h, 2);
  return u;
}
__device__ __forceinline__ void store_out(float* p, float v) { *p = v; }
__device__ __forceinline__ void store_out(bf16* p, float v) { *p = __float2bfloat16(v); }

typedef __attribute__((address_space(3))) void lds_void;
typedef __attribute__((address_space(1))) void gbl_void;

__device__ __forceinline__ void lds_load16(void* l, const void* g) {
  __builtin_amdgcn_global_load_lds((const gbl_void*)g, (lds_void*)l, 16, 0, 0);
}

// ================= 256x256 8-wave pipelined GEMM, f32 A fused-convert =================
// A f32 row-major [M][512]; Bt bf16 row-major [N][512] (read pre-swizzled); C bf16.
// K=512 fixed (nt=8, fully unrolled). A: reg-staged (global f32 -> cvt -> swizzled
// ds_write). B: global_load_lds with inverse-swizzled source. 2-deep K-tile dbuf.
__device__ __forceinline__ void gemm256_xf32(
    const float* __restrict__ Af, int ldA,
    const bf16* __restrict__ Bt, int ldB,
    bf16* C, int ldC, const float* bias, int row0, int col0)
{
  __shared__ bf16 Abuf0[256 * 64], Abuf1[256 * 64];
  __shared__ bf16 Bbuf0[256 * 64], Bbuf1[256 * 64];
  const int tid = threadIdx.x;
  const int lane = tid & 63, w = tid >> 6;
  const int wm = w >> 2, wn = w & 3;
  const int lr = lane & 15, hi = lane >> 4;

  const int stageR = tid >> 3;                          // 0..63
  const int cNat   = (tid & 7) << 3;                    // natural col (A f32 src)
  const int cSwz   = ((tid & 7) ^ (stageR & 7)) << 3;   // swizzled chunk (B src, A LDS dst)
  const float* Ag0 = Af + (size_t)(row0 + stageR) * ldA + cNat;
  const bf16*  Bg0 = Bt + (size_t)(col0 + stageR) * ldB + cSwz;
  const int AwOff = stageR * 64 + cSwz;                 // LDS elem offset (+ q*4096)

  float4 prefE[8], prefO[8];
  auto issueA = [&](float4 (&dst)[8], int k0) {
#pragma unroll
    for (int q = 0; q < 4; ++q) {
      const float* p = Ag0 + (size_t)(q * 64) * ldA + k0;
      dst[q * 2 + 0] = *(const float4*)(p);
      dst[q * 2 + 1] = *(const float4*)(p + 4);
    }
  };
  auto writeA = [&](const float4 (&src)[8], bf16* Al) {
#pragma unroll
    for (int q = 0; q < 4; ++q) {
      float4 v0 = src[q * 2 + 0], v1 = src[q * 2 + 1];
      short8 o;
      o[0] = (short)f2bu(v0.x); o[1] = (short)f2bu(v0.y);
      o[2] = (short)f2bu(v0.z); o[3] = (short)f2bu(v0.w);
      o[4] = (short)f2bu(v1.x); o[5] = (short)f2bu(v1.y);
      o[6] = (short)f2bu(v1.z); o[7] = (short)f2bu(v1.w);
      *(short8*)&Al[AwOff + q * 4096] = o;
    }
  };
  auto stageB = [&](int bsel, int k0) {
    bf16* Bl = (bsel ? Bbuf1 : Bbuf0) + tid * 8;
    const bf16* Bg = Bg0 + k0;
#pragma unroll
    for (int q = 0; q < 4; ++q)
      lds_load16(Bl + q * 4096, Bg + (size_t)(q * 64) * ldB);
  };

  const int aoffb = (wm * 128 + lr) * 128;
  const int boffb = (wn * 64 + lr) * 128;
  const int s0 = ((hi ^ (lr & 7)) << 4);
  const int s1 = (((4 + hi) ^ (lr & 7)) << 4);

  f32x4 acc[8][4];
#pragma unroll
  for (int i = 0; i < 8; ++i)
#pragma unroll
    for (int j = 0; j < 4; ++j) acc[i][j] = (f32x4){0.f, 0.f, 0.f, 0.f};

  // prologue: tiles 0,1 (A via regs, B via gload_lds); prefetch A(2)
  issueA(prefE, 0);
  issueA(prefO, 64);
  stageB(0, 0);
  stageB(1, 64);
  writeA(prefE, Abuf0);          // compiler inserts vmcnt for prefE
  issueA(prefE, 128);            // tile 2 -> slot E
  writeA(prefO, Abuf1);
  asm volatile("s_waitcnt vmcnt(12)" ::: "memory");   // B(0) landed (leaves B1+A2)
  asm volatile("s_waitcnt lgkmcnt(0)" ::: "memory");  // A ds_writes done
  __builtin_amdgcn_s_barrier();

#pragma unroll
  for (int t = 0; t < 8; ++t) {
    if (t + 3 < 8) {
      if (((t + 3) & 1) == 0) issueA(prefE, (t + 3) * 64);
      else                    issueA(prefO, (t + 3) * 64);
    }
    const char* Ab = (const char*)((t & 1) ? Abuf1 : Abuf0);
    const char* Bb = (const char*)((t & 1) ? Bbuf1 : Bbuf0);
    short8 ra[8], rb[4], ra2[8], rb2[4];
#pragma unroll
    for (int fr = 0; fr < 8; ++fr) ra[fr] = *(const short8*)(Ab + aoffb + fr * 2048 + s0);
#pragma unroll
    for (int fq = 0; fq < 4; ++fq) rb[fq] = *(const short8*)(Bb + boffb + fq * 2048 + s0);
    __builtin_amdgcn_s_setprio(1);
#pragma unroll
    for (int fr = 0; fr < 8; ++fr)
#pragma unroll
      for (int fq = 0; fq < 4; ++fq)
        acc[fr][fq] = __builtin_amdgcn_mfma_f32_16x16x32_bf16(ra[fr], rb[fq], acc[fr][fq], 0, 0, 0);
    __builtin_amdgcn_s_setprio(0);
#pragma unroll
    for (int fr = 0; fr < 8; ++fr) ra2[fr] = *(const short8*)(Ab + aoffb + fr * 2048 + s1);
#pragma unroll
    for (int fq = 0; fq < 4; ++fq) rb2[fq] = *(const short8*)(Bb + boffb + fq * 2048 + s1);
    asm volatile("s_waitcnt lgkmcnt(0)" ::: "memory");
    __builtin_amdgcn_s_barrier();
    if (t + 2 < 8) {
      if ((t & 1) == 0) writeA(prefE, Abuf0);   // tile t+2 -> buf[t&1]
      else              writeA(prefO, Abuf1);
      stageB(t & 1, (t + 2) * 64);
    }
    __builtin_amdgcn_s_setprio(1);
#pragma unroll
    for (int fr = 0; fr < 8; ++fr)
#pragma unroll
      for (int fq = 0; fq < 4; ++fq)
        acc[fr][fq] = __builtin_amdgcn_mfma_f32_16x16x32_bf16(ra2[fr], rb2[fq], acc[fr][fq], 0, 0, 0);
    __builtin_amdgcn_s_setprio(0);
    if (t + 1 < 8) {
      if (t + 3 < 8)      asm volatile("s_waitcnt vmcnt(12)" ::: "memory");
      else if (t + 2 < 8) asm volatile("s_waitcnt vmcnt(4)"  ::: "memory");
      else                asm volatile("s_waitcnt vmcnt(0)"  ::: "memory");
      __builtin_amdgcn_s_barrier();
    }
  }

#pragma unroll
  for (int fr = 0; fr < 8; ++fr) {
    const int rowb = row0 + wm * 128 + fr * 16 + hi * 4;
#pragma unroll
    for (int fq = 0; fq < 4; ++fq) {
      const int col = col0 + wn * 64 + fq * 16 + lr;
      const float bv = bias[col];
      f32x4 v = acc[fr][fq];
#pragma unroll
      for (int r = 0; r < 4; ++r)
        store_out(&C[(size_t)(rowb + r) * ldC + col], v[r] + bv);
    }
  }
}

// ================= 128x128 4-wave pipelined GEMM (bf16 A/B, segmented K) =================
// Same barrier/vmcnt structure as the proven 256^2 kernel; 64 KiB LDS -> 2 blocks/CU.
template<typename OutT>
__device__ __forceinline__ void gemm128p(
    const bf16* A0, const bf16* A1, const bf16* A2, const bf16* A3, int ldA,
    const bf16* Bt, int ldB, OutT* C, int ldC, const float* bias,
    int K, int row0, int col0)
{
  __shared__ bf16 Abuf0[128 * 64], Abuf1[128 * 64];
  __shared__ bf16 Bbuf0[128 * 64], Bbuf1[128 * 64];
  const int tid = threadIdx.x;
  const int lane = tid & 63, w = tid >> 6;
  const int wm = w >> 1, wn = w & 1;
  const int lr = lane & 15, hi = lane >> 4;

  const int stageR = tid >> 3;                          // 0..31
  const int stageC = ((tid & 7) ^ (stageR & 7)) << 3;
  const bf16* Bg0 = Bt + (size_t)(col0 + stageR) * ldB + stageC;

  auto stage = [&](int bsel, int k0) {
    const int seg = k0 >> 9;
    const bf16* Aseg = (seg == 0) ? A0 : (seg == 1) ? A1 : (seg == 2) ? A2 : A3;
    const bf16* Ag = Aseg + (size_t)(row0 + stageR) * ldA + (k0 & 511) + stageC;
    const bf16* Bg = Bg0 + k0;
    bf16* Al = (bsel ? Abuf1 : Abuf0) + tid * 8;
    bf16* Bl = (bsel ? Bbuf1 : Bbuf0) + tid * 8;
#pragma unroll
    for (int q = 0; q < 4; ++q) {
      lds_load16(Al + q * 2048, Ag + (size_t)(q * 32) * ldA);
      lds_load16(Bl + q * 2048, Bg + (size_t)(q * 32) * ldB);
    }
  };

  const int aoffb = (wm * 64 + lr) * 128;
  const int boffb = (wn * 64 + lr) * 128;
  const int s0 = ((hi ^ (lr & 7)) << 4);
  const int s1 = (((4 + hi) ^ (lr & 7)) << 4);

  f32x4 acc[4][4];
#pragma unroll
  for (int i = 0; i < 4; ++i)
#pragma unroll
    for (int j = 0; j < 4; ++j) acc[i][j] = (f32x4){0.f, 0.f, 0.f, 0.f};

  const int nt = K >> 6;
  stage(0, 0);
  stage(1, 64);
  asm volatile("s_waitcnt vmcnt(8)" ::: "memory");
  __builtin_amdgcn_s_barrier();

  for (int t = 0; t < nt; ++t) {
    const char* Ab = (const char*)((t & 1) ? Abuf1 : Abuf0);
    const char* Bb = (const char*)((t & 1) ? Bbuf1 : Bbuf0);
    short8 ra[4], rb[4], ra2[4], rb2[4];
#pragma unroll
    for (int fr = 0; fr < 4; ++fr) ra[fr] = *(const short8*)(Ab + aoffb + fr * 2048 + s0);
#pragma unroll
    for (int fq = 0; fq < 4; ++fq) rb[fq] = *(const short8*)(Bb + boffb + fq * 2048 + s0);
    __builtin_amdgcn_s_setprio(1);
#pragma unroll
    for (int fr = 0; fr < 4; ++fr)
#pragma unroll
      for (int fq = 0; fq < 4; ++fq)
        acc[fr][fq] = __builtin_amdgcn_mfma_f32_16x16x32_bf16(ra[fr], rb[fq], acc[fr][fq], 0, 0, 0);
    __builtin_amdgcn_s_setprio(0);
#pragma unroll
    for (int fr = 0; fr < 4; ++fr) ra2[fr] = *(const short8*)(Ab + aoffb + fr * 2048 + s1);
#pragma unroll
    for (int fq = 0; fq < 4; ++fq) rb2[fq] = *(const short8*)(Bb + boffb + fq * 2048 + s1);
    asm volatile("s_waitcnt lgkmcnt(0)" ::: "memory");
    __builtin_amdgcn_s_barrier();
    if (t + 2 < nt) stage(t & 1, (t + 2) << 6);
    __builtin_amdgcn_s_setprio(1);
#pragma unroll
    for (int fr = 0; fr < 4; ++fr)
#pragma unroll
      for (int fq = 0; fq < 4; ++fq)
        acc[fr][fq] = __builtin_amdgcn_mfma_f32_16x16x32_bf16(ra2[fr], rb2[fq], acc[fr][fq], 0, 0, 0);
    __builtin_amdgcn_s_setprio(0);
    if (t + 1 < nt) {
      if (t + 2 < nt) asm volatile("s_waitcnt vmcnt(8)" ::: "memory");
      else            asm volatile("s_waitcnt vmcnt(0)" ::: "memory");
      __builtin_amdgcn_s_barrier();
    }
  }

#pragma unroll
  for (int fr = 0; fr < 4; ++fr) {
    const int rowb = row0 + wm * 64 + fr * 16 + hi * 4;
#pragma unroll
    for (int fq = 0; fq < 4; ++fq) {
      const int col = col0 + wn * 64 + fq * 16 + lr;
      const float bv = bias ? bias[col] : 0.f;
      f32x4 v = acc[fr][fq];
#pragma unroll
      for (int r = 0; r < 4; ++r)
        store_out(&C[(size_t)(rowb + r) * ldC + col], v[r] + bv);
    }
  }
}

// ---------- legacy 128x128 tile (tiny WpfT GEMM) ----------
template<typename OutT>
__device__ __forceinline__ void gemm_tile(
    const bf16* A0, int ldA, const bf16* Bt, int ldB, OutT* C, int ldC,
    const float* bias, int K, int row0, int col0)
{
  __shared__ bf16 As[128 * 32];
  __shared__ bf16 Bs[128 * 32];
  const int t = threadIdx.x;
  const int lane = t & 63;
  const int w = t >> 6;
  const int wm = w >> 1, wn = w & 1;
  const int lr = lane & 15, hi = lane >> 4;
  const int rA = t >> 2;
  const int kA = (t & 3) * 8;

  f32x4 acc[4][4];
#pragma unroll
  for (int i = 0; i < 4; ++i)
#pragma unroll
    for (int j = 0; j < 4; ++j) acc[i][j] = (f32x4){0.f, 0.f, 0.f, 0.f};

  const int nk = K >> 5;
  for (int kt = 0; kt < nk; ++kt) {
    const int k0 = kt << 5;
    __syncthreads();
    lds_load16(&As[t * 8],        A0 + (size_t)(row0 + rA) * ldA + k0 + kA);
    lds_load16(&As[2048 + t * 8], A0 + (size_t)(row0 + 64 + rA) * ldA + k0 + kA);
    lds_load16(&Bs[t * 8],        Bt + (size_t)(col0 + rA) * ldB + k0 + kA);
    lds_load16(&Bs[2048 + t * 8], Bt + (size_t)(col0 + 64 + rA) * ldB + k0 + kA);
    __syncthreads();
    short8 af[4], bfr[4];
#pragma unroll
    for (int f = 0; f < 4; ++f)
      af[f] = *(const short8*)&As[(wm * 64 + f * 16 + lr) * 32 + hi * 8];
#pragma unroll
    for (int f = 0; f < 4; ++f)
      bfr[f] = *(const short8*)&Bs[(wn * 64 + f * 16 + lr) * 32 + hi * 8];
#pragma unroll
    for (int i = 0; i < 4; ++i)
#pragma unroll
      for (int j = 0; j < 4; ++j)
        acc[i][j] = __builtin_amdgcn_mfma_f32_16x16x32_bf16(af[i], bfr[j], acc[i][j], 0, 0, 0);
  }

#pragma unroll
  for (int i = 0; i < 4; ++i) {
    const int rowb = row0 + wm * 64 + i * 16 + hi * 4;
#pragma unroll
    for (int j = 0; j < 4; ++j) {
      const int col = col0 + wn * 64 + j * 16 + lr;
      const float bv = bias ? bias[col] : 0.f;
      f32x4 v = acc[i][j];
#pragma unroll
      for (int r = 0; r < 4; ++r)
        store_out(&C[(size_t)(rowb + r) * ldC + col], v[r] + bv);
    }
  }
}

// ---------- conversion kernels ----------
// out[b][c][r] = in[b][r][c]  (transpose + f32->bf16), LDS-tiled 64x64
__global__ __launch_bounds__(256) void k_transpose(
    const float* __restrict__ in, bf16* __restrict__ out, int R, int C)
{
  const int tilesC = C >> 6;
  const int tr = (blockIdx.x / tilesC) << 6;
  const int tc = (blockIdx.x % tilesC) << 6;
  const size_t base = (size_t)blockIdx.y * R * C;
  __shared__ unsigned short tile[64][72];
  const int rr = threadIdx.x >> 4;
  const int cc = (threadIdx.x & 15) << 2;
#pragma unroll
  for (int p = 0; p < 4; ++p) {
    const int r = rr + (p << 4);
    float4 v = *(const float4*)&in[base + (size_t)(tr + r) * C + tc + cc];
    tile[cc + 0][r] = f2bu(v.x);
    tile[cc + 1][r] = f2bu(v.y);
    tile[cc + 2][r] = f2bu(v.z);
    tile[cc + 3][r] = f2bu(v.w);
  }
  __syncthreads();
#pragma unroll
  for (int p = 0; p < 4; ++p) {
    const int r = rr + (p << 4);
    ushort4 o;
    o.x = tile[r][cc + 0];
    o.y = tile[r][cc + 1];
    o.z = tile[r][cc + 2];
    o.w = tile[r][cc + 3];
    *(ushort4*)&out[base + (size_t)(tc + r) * R + tr + cc] = o;
  }
}

__global__ __launch_bounds__(256) void k_copy_bf16(
    const float* __restrict__ in, bf16* __restrict__ out)
{
  const long long i = (long long)blockIdx.x * 256 + threadIdx.x;
  float4 v = ((const float4*)in)[i];
  ushort4 o;
  o.x = f2bu(v.x); o.y = f2bu(v.y); o.z = f2bu(v.z); o.w = f2bu(v.w);
  ((ushort4*)out)[i] = o;
}

// b'[m][n] = (sum_j bp[m,j,:]) @ Wf[fidx[m]] + bf[fidx[m]]   (bpr pre-zeroed)
__global__ __launch_bounds__(256) void k_bprime(
    const float* __restrict__ bp, const float* __restrict__ Wf,
    const float* __restrict__ bfv, float* __restrict__ bpr)
{
  const int m = blockIdx.x;
  const int dc = blockIdx.y;
  const int n = threadIdx.x;
  const int fi = (m == 0) ? 0 : 1;
  float s = (dc == 0) ? bfv[fi * 256 + n] : 0.f;
  for (int d = dc * 64; d < dc * 64 + 64; ++d) {
    float b3 = bp[(m * 3 + 0) * 512 + d] + bp[(m * 3 + 1) * 512 + d] +
               bp[(m * 3 + 2) * 512 + d];
    s += b3 * Wf[(size_t)fi * 512 * 256 + (size_t)d * 256 + n];
  }
  atomicAdd(&bpr[m * 256 + n], s);
}

// ---------- GEMM wrappers ----------
// 768 blocks, XCD-chunked swizzle; A read directly from f32 X (fused convert).
__global__ __launch_bounds__(512, 2) void k_gemm1(
    const float* __restrict__ x0, const float* __restrict__ x1,
    const float* __restrict__ x2, const bf16* __restrict__ WT,
    const float* __restrict__ bq, const float* __restrict__ bk,
    bf16* __restrict__ QK)
{
  const int bid = blockIdx.x;
  const int swz = (bid & 7) * 96 + (bid >> 3);
  const int m = swz >> 8;
  const int rem = swz & 255;
  const int tm = rem >> 2;
  const int tn = (rem >> 1) & 1;
  const int qk = rem & 1;
  const int inst = qk ? (m + 3) : m;
  const float* A = (m == 0) ? x0 : (m == 1) ? x1 : x2;
  const bf16* B = WT + (size_t)inst * (512 * 512);
  const float* bias = (qk ? bk : bq) + m * 512;
  bf16* C = QK + (size_t)inst * (16384 * 512);
  gemm256_xf32(A, 512, B, 512, C, 512, bias, tm * 256, tn * 256);
}

// WpfT[m,j] = Wf^T @ Wp^T  (tiny)
__global__ __launch_bounds__(256) void k_gemm_wpf(
    const bf16* __restrict__ WfT, const bf16* __restrict__ Wpbf,
    float* __restrict__ WpfT)
{
  const int inst = blockIdx.y;
  const int m = inst / 3;
  const int fi = (m == 0) ? 0 : 1;
  const int tm = blockIdx.x >> 2, tn = blockIdx.x & 3;
  const bf16* A = WfT + (size_t)fi * (256 * 512);
  const bf16* B = Wpbf + (size_t)inst * (512 * 512);
  float* C = WpfT + (size_t)inst * (256 * 512);
  gemm_tile<float>(A, 512, B, 512, C, 512, nullptr, 512, tm * 128, tn * 128);
}

// out[m,b] = [Q[m][b] | K0[b] | K1[b] | K2[b]] (1024x2048) @ W2T[m,b]^T + b'[m]
// 768 blocks of 256 thr (128^2 tiles, 2 blocks/CU), XCD-chunked swizzle.
__global__ __launch_bounds__(256, 2) void k_gemm2(
    const bf16* __restrict__ QK, const bf16* __restrict__ W2T,
    const float* __restrict__ bpr, float* __restrict__ out)
{
  const int bid = blockIdx.x;
  const int swz = (bid & 7) * 96 + (bid >> 3);
  const int e = swz >> 4;          // m*16+b grouping: 16 tiles per e
  const int tm = (swz >> 1) & 7;
  const int tn = swz & 1;
  const int m = e / 16, b = e & 15;
  const bf16* A0 = QK + ((size_t)m * 16384 + (size_t)b * 1024) * 512;
  const bf16* A1 = QK + ((size_t)(3 * 16384) + (size_t)b * 1024) * 512;
  const bf16* A2 = QK + ((size_t)(4 * 16384) + (size_t)b * 1024) * 512;
  const bf16* A3 = QK + ((size_t)(5 * 16384) + (size_t)b * 1024) * 512;
  const bf16* Bt = W2T + (size_t)e * (256 * 2048);
  float* C = out + (size_t)e * (1024 * 256);
  gemm128p<float>(A0, A1, A2, A3, 512, Bt, 2048, C, 256, bpr + m * 256, 2048,
                  tm * 128, tn * 128);
}

// ---------- row L2-normalize (in place, bf16) + q_dot for Q tensors ----------
__global__ __launch_bounds__(256) void k_norm(
    bf16* __restrict__ QK, const float* __restrict__ wg, float* __restrict__ qdot)
{
  const int row = blockIdx.x * 4 + (threadIdx.x >> 6);
  const int lane = threadIdx.x & 63;
  bf16* p = QK + (size_t)row * 512 + lane * 8;
  short8 v = *(const short8*)p;
  float f[8];
  float ss = 0.f;
#pragma unroll
  for (int i = 0; i < 8; ++i) { f[i] = b2f(v[i]); ss += f[i] * f[i]; }
#pragma unroll
  for (int o = 32; o; o >>= 1) ss += __shfl_xor(ss, o);
  const float inv = 1.f / fmaxf(sqrtf(ss), 1e-12f);
  short8 ov;
#pragma unroll
  for (int i = 0; i < 8; ++i) ov[i] = (short)f2bu(f[i] * inv);
  *(short8*)p = ov;
  const int tt = row >> 14;
  if (tt < 3) {
    const float* wgm = wg + (size_t)tt * 512 + lane * 8;
    float dot = 0.f;
#pragma unroll
    for (int i = 0; i < 8; ++i) dot += f[i] * wgm[i];
    dot *= inv;
#pragma unroll
    for (int o = 32; o; o >>= 1) dot += __shfl_xor(dot, o);
    if (lane == 0) qdot[row] = dot;
  }
}

// ---------- gate ----------
__global__ __launch_bounds__(256) void k_G(
    const float* __restrict__ qdot, const bf16* __restrict__ QK, float* __restrict__ G)
{
  const int e = blockIdx.x;       // m*16+b
  const int m = e >> 4, b = e & 15;
  const int d0 = blockIdx.y << 6;
  __shared__ float Al[1024];
  __shared__ float red[4];
  __shared__ float Gp[4][64];
  const int t = threadIdx.x;
  const float* qd = qdot + (size_t)m * 16384 + (size_t)b * 1024;
  float ss = 0.f;
#pragma unroll
  for (int i = 0; i < 4; ++i) {
    float x = qd[t + i * 256] * SCALE_F;
    Al[t + i * 256] = x;
    ss += x * x;
  }
#pragma unroll
  for (int o = 32; o; o >>= 1) ss += __shfl_xor(ss, o);
  if ((t & 63) == 0) red[t >> 6] = ss;
  __syncthreads();
  const float inv = 1.f / fmaxf(sqrtf(red[0] + red[1] + red[2] + red[3]), 1e-12f);

  const int d = d0 + (t & 63);
  const int q = t >> 6;
  const bf16* Qb = QK + ((size_t)m * 16384 + (size_t)b * 1024) * 512 + d;
  float g = 0.f;
  for (int n = q * 256; n < q * 256 + 256; ++n)
    g += Al[n] * b2f(*(const short*)&Qb[(size_t)n * 512]);
  Gp[q][t & 63] = g;
  __syncthreads();
  if (t < 64)
    G[(size_t)e * 512 + d0 + t] = (Gp[0][t] + Gp[1][t] + Gp[2][t] + Gp[3][t]) * inv;
}

// ---------- W2T[m,b] [256][2048] bf16 ----------
__global__ __launch_bounds__(256) void k_w2t(
    const bf16* __restrict__ WfT, const float* __restrict__ WpfT,
    const float* __restrict__ G, bf16* __restrict__ W2T)
{
  const int e = blockIdx.x;
  const int m = e >> 4;
  const int fi = (m == 0) ? 0 : 1;
  const int t = threadIdx.x;
  bf16* out = W2T + (size_t)e * (256 * 2048);
  __shared__ float Gl[512];
  Gl[t] = G[(size_t)e * 512 + t];
  Gl[t + 256] = G[(size_t)e * 512 + t + 256];
  __syncthreads();
  const int k = t * 8;
  for (int nr = 0; nr < 16; ++nr) {
    const int n = blockIdx.y * 16 + nr;
    if (k < 512) {
      *(short8*)&out[(size_t)n * 2048 + k] =
          *(const short8*)&WfT[((size_t)fi * 256 + n) * 512 + k];
    } else {
      const int j = (k >> 9) - 1;
      const int d = k & 511;
      const float* src = WpfT + (((size_t)(m * 3 + j) * 256 + n) * 512 + d);
      short8 o;
#pragma unroll
      for (int i = 0; i < 8; ++i) o[i] = (short)f2bu(Gl[d + i] * src[i]);
      *(short8*)&out[(size_t)n * 2048 + k] = o;
    }
  }
}

// ---------- launch ----------
extern "C" void kernel_launch(void* const* d_in, const int* in_sizes, int n_in,
                              void* d_out, int out_size, void* d_ws, size_t ws_size,
                              hipStream_t stream) {
  const float* x_lv = (const float*)d_in[0];
  const float* x_myo = (const float*)d_in[1];
  const float* x_rv = (const float*)d_in[2];
  const float* Wq = (const float*)d_in[3];
  const float* bq = (const float*)d_in[4];
  const float* Wk = (const float*)d_in[5];
  const float* bk = (const float*)d_in[6];
  const float* wg = (const float*)d_in[7];
  const float* Wp = (const float*)d_in[8];
  const float* bp = (const float*)d_in[9];
  const float* Wf = (const float*)d_in[10];
  const float* bfv = (const float*)d_in[11];
  float* out = (float*)d_out;

  char* ws = (char*)d_ws;
  bf16* QK    = (bf16*)(ws);                      // 6*16384*512*2 = 100663296
  bf16* W2T   = (bf16*)(ws + 100663296);          // 48*256*2048*2 = 50331648
  bf16* WT    = (bf16*)(ws + 150994944);          // 6*512*512*2   = 3145728
  bf16* Wpbf  = (bf16*)(ws + 154140672);          // 9*512*512*2   = 4718592
  bf16* WfT   = (bf16*)(ws + 158859264);          // 2*256*512*2   = 524288
  float* WpfT = (float*)(ws + 159383552);         // 9*256*512*4   = 4718592
  float* qdot = (float*)(ws + 164102144);         // 3*16384*4     = 196608
  float* G    = (float*)(ws + 164298752);         // 48*512*4      = 98304
  float* bpr  = (float*)(ws + 164397056);         // 3*256*4       = 3072

  // weight conversions
  k_transpose<<<dim3(64, 3), 256, 0, stream>>>(Wq, WT, 512, 512);
  k_transpose<<<dim3(64, 3), 256, 0, stream>>>(Wk, WT + 3 * 512 * 512, 512, 512);
  k_transpose<<<dim3(32, 2), 256, 0, stream>>>(Wf, WfT, 512, 256);
  k_copy_bf16<<<2304, 256, 0, stream>>>(Wp, Wpbf);
  hipMemsetAsync(bpr, 0, 3 * 256 * sizeof(float), stream);
  k_bprime<<<dim3(3, 8), 256, 0, stream>>>(bp, Wf, bfv, bpr);

  // projections (6 GEMMs of 16384x512x512) -> QK; f32 X read + convert fused
  k_gemm1<<<768, 512, 0, stream>>>(x_lv, x_myo, x_rv, WT, bq, bk, QK);

  // normalize rows in place + q_dot
  k_norm<<<24576, 256, 0, stream>>>(QK, wg, qdot);

  // WpfT = Wf^T @ Wp^T (9 GEMMs of 256x512x512)
  k_gemm_wpf<<<dim3(8, 9), 256, 0, stream>>>(WfT, Wpbf, WpfT);

  // gate G per (m,b), 8 d-chunks
  k_G<<<dim3(48, 8), 256, 0, stream>>>(qdot, QK, G);

  // per-(m,b) stacked weights
  k_w2t<<<dim3(48, 16), 256, 0, stream>>>(WfT, WpfT, G, W2T);

  // final batched GEMM: 48 x (1024x256, K=2048) -> out, 128^2 pipelined, 2/CU
  k_gemm2<<<768, 256, 0, stream>>>(QK, W2T, bpr, out);
}

// Round 12
// 366.423 us; speedup vs baseline: 1.0611x; 1.0611x over previous
//
#include <hip/hip_runtime.h>
#include <hip/hip_bf16.h>

typedef __hip_bfloat16 bf16;
typedef __attribute__((ext_vector_type(8))) short short8;
typedef __attribute__((ext_vector_type(4))) float f32x4;

#define SCALE_F 0.0625f   // 256^-0.5

// ---------- small helpers ----------
__device__ __forceinline__ float b2f(short s) {
  union { float f; unsigned int u; } x;
  x.u = ((unsigned int)(unsigned short)s) << 16;
  return x.f;
}
__device__ __forceinline__ unsigned short f2bu(float f) {
  __hip_bfloat16 h = __float2bfloat16(f);
  unsigned short u;
  __builtin_memcpy(&u, &h, 2);
  return u;
}
__device__ __forceinline__ void store_out(float* p, float v) { *p = v; }
__device__ __forceinline__ void store_out(bf16* p, float v) { *p = __float2bfloat16(v); }

typedef __attribute__((address_space(3))) void lds_void;
typedef __attribute__((address_space(1))) void gbl_void;

__device__ __forceinline__ void lds_load16(void* l, const void* g) {
  __builtin_amdgcn_global_load_lds((const gbl_void*)g, (lds_void*)l, 16, 0, 0);
}

// ================= 256x256 8-wave pipelined GEMM (round-6 proven: 72.3us) =================
// A row-major [M][K] (4 K-segments of 512), Bt row-major [N][K], C [M][N].
// BK=64, 2-deep K-tile double buffer, counted vmcnt(8), raw barriers,
// LDS XOR-swizzle (linear gload_lds dest + inverse-swizzled global src).
template<typename OutT>
__device__ __forceinline__ void gemm256_tile(
    const bf16* A0, const bf16* A1, const bf16* A2, const bf16* A3, int ldA,
    const bf16* Bt, int ldB, OutT* C, int ldC, const float* bias,
    int K, int row0, int col0)
{
  __shared__ bf16 Abuf0[256 * 64], Abuf1[256 * 64];
  __shared__ bf16 Bbuf0[256 * 64], Bbuf1[256 * 64];
  const int tid = threadIdx.x;
  const int lane = tid & 63, w = tid >> 6;
  const int wm = w >> 2, wn = w & 3;          // 2 x 4 wave grid
  const int lr = lane & 15, hi = lane >> 4;

  const int stageR = tid >> 3;                          // row within 64-row group
  const int stageC = ((tid & 7) ^ (stageR & 7)) << 3;   // pre-swizzled k-chunk
  const bf16* Bg0 = Bt + (size_t)(col0 + stageR) * ldB + stageC;

  auto stage = [&](int bsel, int k0) {
    const int seg = k0 >> 9;
    const bf16* Aseg = (seg == 0) ? A0 : (seg == 1) ? A1 : (seg == 2) ? A2 : A3;
    const bf16* Ag = Aseg + (size_t)(row0 + stageR) * ldA + (k0 & 511) + stageC;
    const bf16* Bg = Bg0 + k0;
    bf16* Al = (bsel ? Abuf1 : Abuf0) + tid * 8;
    bf16* Bl = (bsel ? Bbuf1 : Bbuf0) + tid * 8;
#pragma unroll
    for (int q = 0; q < 4; ++q) {
      lds_load16(Al + q * 4096, Ag + (size_t)q * 64 * ldA);
      lds_load16(Bl + q * 4096, Bg + (size_t)q * 64 * ldB);
    }
  };

  const int aoffb = (wm * 128 + lr) * 128;
  const int boffb = (wn * 64 + lr) * 128;
  const int s0 = ((hi ^ (lr & 7)) << 4);
  const int s1 = (((4 + hi) ^ (lr & 7)) << 4);

  f32x4 acc[8][4];
#pragma unroll
  for (int i = 0; i < 8; ++i)
#pragma unroll
    for (int j = 0; j < 4; ++j) acc[i][j] = (f32x4){0.f, 0.f, 0.f, 0.f};

  const int nt = K >> 6;
  stage(0, 0);
  stage(1, 64);
  asm volatile("s_waitcnt vmcnt(8)" ::: "memory");
  __builtin_amdgcn_s_barrier();

  for (int t = 0; t < nt; ++t) {
    const char* Ab = (const char*)((t & 1) ? Abuf1 : Abuf0);
    const char* Bb = (const char*)((t & 1) ? Bbuf1 : Bbuf0);
    short8 ra[8], rb[4], ra2[8], rb2[4];
#pragma unroll
    for (int fr = 0; fr < 8; ++fr) ra[fr] = *(const short8*)(Ab + aoffb + fr * 2048 + s0);
#pragma unroll
    for (int fq = 0; fq < 4; ++fq) rb[fq] = *(const short8*)(Bb + boffb + fq * 2048 + s0);
    __builtin_amdgcn_s_setprio(1);
#pragma unroll
    for (int fr = 0; fr < 8; ++fr)
#pragma unroll
      for (int fq = 0; fq < 4; ++fq)
        acc[fr][fq] = __builtin_amdgcn_mfma_f32_16x16x32_bf16(ra[fr], rb[fq], acc[fr][fq], 0, 0, 0);
    __builtin_amdgcn_s_setprio(0);
#pragma unroll
    for (int fr = 0; fr < 8; ++fr) ra2[fr] = *(const short8*)(Ab + aoffb + fr * 2048 + s1);
#pragma unroll
    for (int fq = 0; fq < 4; ++fq) rb2[fq] = *(const short8*)(Bb + boffb + fq * 2048 + s1);
    asm volatile("s_waitcnt lgkmcnt(0)" ::: "memory");
    __builtin_amdgcn_s_barrier();
    if (t + 2 < nt) stage(t & 1, (t + 2) << 6);
    __builtin_amdgcn_s_setprio(1);
#pragma unroll
    for (int fr = 0; fr < 8; ++fr)
#pragma unroll
      for (int fq = 0; fq < 4; ++fq)
        acc[fr][fq] = __builtin_amdgcn_mfma_f32_16x16x32_bf16(ra2[fr], rb2[fq], acc[fr][fq], 0, 0, 0);
    __builtin_amdgcn_s_setprio(0);
    if (t + 1 < nt) {
      if (t + 2 < nt) asm volatile("s_waitcnt vmcnt(8)" ::: "memory");
      else            asm volatile("s_waitcnt vmcnt(0)" ::: "memory");
      __builtin_amdgcn_s_barrier();
    }
  }

#pragma unroll
  for (int fr = 0; fr < 8; ++fr) {
    const int rowb = row0 + wm * 128 + fr * 16 + hi * 4;
#pragma unroll
    for (int fq = 0; fq < 4; ++fq) {
      const int col = col0 + wn * 64 + fq * 16 + lr;
      const float bv = bias ? bias[col] : 0.f;
      f32x4 v = acc[fr][fq];
#pragma unroll
      for (int r = 0; r < 4; ++r)
        store_out(&C[(size_t)(rowb + r) * ldC + col], v[r] + bv);
    }
  }
}

// ================= 128x128 4-wave pipelined GEMM (BREP bias partials) =================
template<typename OutT, int BREP>
__device__ __forceinline__ void gemm128p(
    const bf16* A0, const bf16* A1, const bf16* A2, const bf16* A3, int ldA,
    const bf16* Bt, int ldB, OutT* C, int ldC, const float* bias,
    int K, int row0, int col0)
{
  __shared__ bf16 Abuf0[128 * 64], Abuf1[128 * 64];
  __shared__ bf16 Bbuf0[128 * 64], Bbuf1[128 * 64];
  const int tid = threadIdx.x;
  const int lane = tid & 63, w = tid >> 6;
  const int wm = w >> 1, wn = w & 1;
  const int lr = lane & 15, hi = lane >> 4;

  const int stageR = tid >> 3;
  const int stageC = ((tid & 7) ^ (stageR & 7)) << 3;
  const bf16* Bg0 = Bt + (size_t)(col0 + stageR) * ldB + stageC;

  auto stage = [&](int bsel, int k0) {
    const int seg = k0 >> 9;
    const bf16* Aseg = (seg == 0) ? A0 : (seg == 1) ? A1 : (seg == 2) ? A2 : A3;
    const bf16* Ag = Aseg + (size_t)(row0 + stageR) * ldA + (k0 & 511) + stageC;
    const bf16* Bg = Bg0 + k0;
    bf16* Al = (bsel ? Abuf1 : Abuf0) + tid * 8;
    bf16* Bl = (bsel ? Bbuf1 : Bbuf0) + tid * 8;
#pragma unroll
    for (int q = 0; q < 4; ++q) {
      lds_load16(Al + q * 2048, Ag + (size_t)(q * 32) * ldA);
      lds_load16(Bl + q * 2048, Bg + (size_t)(q * 32) * ldB);
    }
  };

  const int aoffb = (wm * 64 + lr) * 128;
  const int boffb = (wn * 64 + lr) * 128;
  const int s0 = ((hi ^ (lr & 7)) << 4);
  const int s1 = (((4 + hi) ^ (lr & 7)) << 4);

  f32x4 acc[4][4];
#pragma unroll
  for (int i = 0; i < 4; ++i)
#pragma unroll
    for (int j = 0; j < 4; ++j) acc[i][j] = (f32x4){0.f, 0.f, 0.f, 0.f};

  const int nt = K >> 6;
  stage(0, 0);
  stage(1, 64);
  asm volatile("s_waitcnt vmcnt(8)" ::: "memory");
  __builtin_amdgcn_s_barrier();

  for (int t = 0; t < nt; ++t) {
    const char* Ab = (const char*)((t & 1) ? Abuf1 : Abuf0);
    const char* Bb = (const char*)((t & 1) ? Bbuf1 : Bbuf0);
    short8 ra[4], rb[4], ra2[4], rb2[4];
#pragma unroll
    for (int fr = 0; fr < 4; ++fr) ra[fr] = *(const short8*)(Ab + aoffb + fr * 2048 + s0);
#pragma unroll
    for (int fq = 0; fq < 4; ++fq) rb[fq] = *(const short8*)(Bb + boffb + fq * 2048 + s0);
    __builtin_amdgcn_s_setprio(1);
#pragma unroll
    for (int fr = 0; fr < 4; ++fr)
#pragma unroll
      for (int fq = 0; fq < 4; ++fq)
        acc[fr][fq] = __builtin_amdgcn_mfma_f32_16x16x32_bf16(ra[fr], rb[fq], acc[fr][fq], 0, 0, 0);
    __builtin_amdgcn_s_setprio(0);
#pragma unroll
    for (int fr = 0; fr < 4; ++fr) ra2[fr] = *(const short8*)(Ab + aoffb + fr * 2048 + s1);
#pragma unroll
    for (int fq = 0; fq < 4; ++fq) rb2[fq] = *(const short8*)(Bb + boffb + fq * 2048 + s1);
    asm volatile("s_waitcnt lgkmcnt(0)" ::: "memory");
    __builtin_amdgcn_s_barrier();
    if (t + 2 < nt) stage(t & 1, (t + 2) << 6);
    __builtin_amdgcn_s_setprio(1);
#pragma unroll
    for (int fr = 0; fr < 4; ++fr)
#pragma unroll
      for (int fq = 0; fq < 4; ++fq)
        acc[fr][fq] = __builtin_amdgcn_mfma_f32_16x16x32_bf16(ra2[fr], rb2[fq], acc[fr][fq], 0, 0, 0);
    __builtin_amdgcn_s_setprio(0);
    if (t + 1 < nt) {
      if (t + 2 < nt) asm volatile("s_waitcnt vmcnt(8)" ::: "memory");
      else            asm volatile("s_waitcnt vmcnt(0)" ::: "memory");
      __builtin_amdgcn_s_barrier();
    }
  }

#pragma unroll
  for (int fr = 0; fr < 4; ++fr) {
    const int rowb = row0 + wm * 64 + fr * 16 + hi * 4;
#pragma unroll
    for (int fq = 0; fq < 4; ++fq) {
      const int col = col0 + wn * 64 + fq * 16 + lr;
      float bv = 0.f;
      if (bias) {
#pragma unroll
        for (int i = 0; i < BREP; ++i) bv += bias[i * 256 + col];
      }
      f32x4 v = acc[fr][fq];
#pragma unroll
      for (int r = 0; r < 4; ++r)
        store_out(&C[(size_t)(rowb + r) * ldC + col], v[r] + bv);
    }
  }
}

// ---------- legacy 128x128 tile (tiny WpfT GEMM) ----------
template<typename OutT>
__device__ __forceinline__ void gemm_tile(
    const bf16* A0, int ldA, const bf16* Bt, int ldB, OutT* C, int ldC,
    const float* bias, int K, int row0, int col0)
{
  __shared__ bf16 As[128 * 32];
  __shared__ bf16 Bs[128 * 32];
  const int t = threadIdx.x;
  const int lane = t & 63;
  const int w = t >> 6;
  const int wm = w >> 1, wn = w & 1;
  const int lr = lane & 15, hi = lane >> 4;
  const int rA = t >> 2;
  const int kA = (t & 3) * 8;

  f32x4 acc[4][4];
#pragma unroll
  for (int i = 0; i < 4; ++i)
#pragma unroll
    for (int j = 0; j < 4; ++j) acc[i][j] = (f32x4){0.f, 0.f, 0.f, 0.f};

  const int nk = K >> 5;
  for (int kt = 0; kt < nk; ++kt) {
    const int k0 = kt << 5;
    __syncthreads();
    lds_load16(&As[t * 8],        A0 + (size_t)(row0 + rA) * ldA + k0 + kA);
    lds_load16(&As[2048 + t * 8], A0 + (size_t)(row0 + 64 + rA) * ldA + k0 + kA);
    lds_load16(&Bs[t * 8],        Bt + (size_t)(col0 + rA) * ldB + k0 + kA);
    lds_load16(&Bs[2048 + t * 8], Bt + (size_t)(col0 + 64 + rA) * ldB + k0 + kA);
    __syncthreads();
    short8 af[4], bfr[4];
#pragma unroll
    for (int f = 0; f < 4; ++f)
      af[f] = *(const short8*)&As[(wm * 64 + f * 16 + lr) * 32 + hi * 8];
#pragma unroll
    for (int f = 0; f < 4; ++f)
      bfr[f] = *(const short8*)&Bs[(wn * 64 + f * 16 + lr) * 32 + hi * 8];
#pragma unroll
    for (int i = 0; i < 4; ++i)
#pragma unroll
      for (int j = 0; j < 4; ++j)
        acc[i][j] = __builtin_amdgcn_mfma_f32_16x16x32_bf16(af[i], bfr[j], acc[i][j], 0, 0, 0);
  }

#pragma unroll
  for (int i = 0; i < 4; ++i) {
    const int rowb = row0 + wm * 64 + i * 16 + hi * 4;
#pragma unroll
    for (int j = 0; j < 4; ++j) {
      const int col = col0 + wn * 64 + j * 16 + lr;
      const float bv = bias ? bias[col] : 0.f;
      f32x4 v = acc[i][j];
#pragma unroll
      for (int r = 0; r < 4; ++r)
        store_out(&C[(size_t)(rowb + r) * ldC + col], v[r] + bv);
    }
  }
}

// ---------- fused prep: X convert + W transposes + Wp copy + bprime partials ----------
// grid 25624 x 256:
//   [0,192)      Wq transpose (3 batches x 64 tiles)
//   [192,384)    Wk transpose
//   [384,448)    Wf transpose (2 batches x 32 tiles)
//   [448,1024)   Wp f32->bf16 copy (576 blocks, 4 float4/thread)
//   [1024,1048)  bprime partials (3 m x 8 d-chunks)
//   [1048,25624) X f32->bf16 convert (24576 blocks)
__global__ __launch_bounds__(256) void k_prep(
    const float* __restrict__ x0, const float* __restrict__ x1,
    const float* __restrict__ x2, bf16* __restrict__ xbf,
    const float* __restrict__ Wq, const float* __restrict__ Wk,
    const float* __restrict__ Wf, const float* __restrict__ Wp,
    const float* __restrict__ bp, const float* __restrict__ bfv,
    bf16* __restrict__ WT, bf16* __restrict__ WfT,
    bf16* __restrict__ Wpbf, float* __restrict__ bprp)
{
  __shared__ unsigned short tile[64][72];
  const int bid = blockIdx.x;
  const int t = threadIdx.x;

  if (bid >= 1048) {                       // ---- X convert ----
    const long long i = (long long)(bid - 1048) * 256 + t;
    const int tt = (int)(i / 2097152);
    const long long e = i - (long long)tt * 2097152;
    const float4* src = (const float4*)(tt == 0 ? x0 : tt == 1 ? x1 : x2);
    float4 v = src[e];
    ushort4 o;
    o.x = f2bu(v.x); o.y = f2bu(v.y); o.z = f2bu(v.z); o.w = f2bu(v.w);
    ((ushort4*)xbf)[i] = o;
    return;
  }
  if (bid < 448) {                         // ---- transposes ----
    const float* in; bf16* out; int R, C, ti;
    if (bid < 192)      { in = Wq + (bid / 64) * 262144; out = WT + (bid / 64) * 262144; R = 512; C = 512; ti = bid & 63; }
    else if (bid < 384) { int b2 = bid - 192; in = Wk + (b2 / 64) * 262144; out = WT + (3 + b2 / 64) * 262144; R = 512; C = 512; ti = b2 & 63; }
    else                { int b2 = bid - 384; in = Wf + (b2 / 32) * 131072; out = WfT + (b2 / 32) * 131072; R = 512; C = 256; ti = b2 & 31; }
    const int tilesC = C >> 6;
    const int tr = (ti / tilesC) << 6;
    const int tc = (ti % tilesC) << 6;
    const int rr = t >> 4;
    const int cc = (t & 15) << 2;
#pragma unroll
    for (int p = 0; p < 4; ++p) {
      const int r = rr + (p << 4);
      float4 v = *(const float4*)&in[(size_t)(tr + r) * C + tc + cc];
      tile[cc + 0][r] = f2bu(v.x);
      tile[cc + 1][r] = f2bu(v.y);
      tile[cc + 2][r] = f2bu(v.z);
      tile[cc + 3][r] = f2bu(v.w);
    }
    __syncthreads();
#pragma unroll
    for (int p = 0; p < 4; ++p) {
      const int r = rr + (p << 4);
      ushort4 o;
      o.x = tile[r][cc + 0];
      o.y = tile[r][cc + 1];
      o.z = tile[r][cc + 2];
      o.w = tile[r][cc + 3];
      *(ushort4*)&out[(size_t)(tc + r) * R + tr + cc] = o;
    }
    return;
  }
  if (bid < 1024) {                        // ---- Wp copy ----
    const int base = (bid - 448) * 256 + t;
#pragma unroll
    for (int s = 0; s < 4; ++s) {
      const int i = base + s * 147456;
      float4 v = ((const float4*)Wp)[i];
      ushort4 o;
      o.x = f2bu(v.x); o.y = f2bu(v.y); o.z = f2bu(v.z); o.w = f2bu(v.w);
      ((ushort4*)Wpbf)[i] = o;
    }
    return;
  }
  {                                        // ---- bprime partials ----
    const int mm = (bid - 1024) >> 3, dc = (bid - 1024) & 7;
    const int n = t;
    const int fi = (mm == 0) ? 0 : 1;
    float s = (dc == 0) ? bfv[fi * 256 + n] : 0.f;
    for (int d = dc * 64; d < dc * 64 + 64; ++d) {
      float b3 = bp[(mm * 3 + 0) * 512 + d] + bp[(mm * 3 + 1) * 512 + d] +
                 bp[(mm * 3 + 2) * 512 + d];
      s += b3 * Wf[(size_t)fi * 512 * 256 + (size_t)d * 256 + n];
    }
    bprp[(mm * 8 + dc) * 256 + n] = s;
  }
}

// ---------- GEMM wrappers ----------
__global__ __launch_bounds__(512, 2) void k_gemm1(
    const bf16* __restrict__ Xbf, const bf16* __restrict__ WT,
    const float* __restrict__ bq, const float* __restrict__ bk,
    bf16* __restrict__ QK)
{
  const int bid = blockIdx.x;
  const int swz = (bid & 7) * 96 + (bid >> 3);
  const int m = swz >> 8;
  const int rem = swz & 255;
  const int tm = rem >> 2;
  const int tn = (rem >> 1) & 1;
  const int qk = rem & 1;
  const int inst = qk ? (m + 3) : m;
  const bf16* A = Xbf + (size_t)m * (16384 * 512);
  const bf16* B = WT + (size_t)inst * (512 * 512);
  const float* bias = (qk ? bk : bq) + m * 512;
  bf16* C = QK + (size_t)inst * (16384 * 512);
  gemm256_tile<bf16>(A, A, A, A, 512, B, 512, C, 512, bias, 512, tm * 256, tn * 256);
}

__global__ __launch_bounds__(256) void k_gemm_wpf(
    const bf16* __restrict__ WfT, const bf16* __restrict__ Wpbf,
    float* __restrict__ WpfT)
{
  const int inst = blockIdx.y;
  const int m = inst / 3;
  const int fi = (m == 0) ? 0 : 1;
  const int tm = blockIdx.x >> 2, tn = blockIdx.x & 3;
  const bf16* A = WfT + (size_t)fi * (256 * 512);
  const bf16* B = Wpbf + (size_t)inst * (512 * 512);
  float* C = WpfT + (size_t)inst * (256 * 512);
  gemm_tile<float>(A, 512, B, 512, C, 512, nullptr, 512, tm * 128, tn * 128);
}

// 768 blocks of 256 thr (128^2 tiles, 2 blocks/CU), XCD-chunked swizzle.
__global__ __launch_bounds__(256, 2) void k_gemm2(
    const bf16* __restrict__ QK, const bf16* __restrict__ W2T,
    const float* __restrict__ bprp, float* __restrict__ out)
{
  const int bid = blockIdx.x;
  const int swz = (bid & 7) * 96 + (bid >> 3);
  const int e = swz >> 4;
  const int tm = (swz >> 1) & 7;
  const int tn = swz & 1;
  const int m = e / 16, b = e & 15;
  const bf16* A0 = QK + ((size_t)m * 16384 + (size_t)b * 1024) * 512;
  const bf16* A1 = QK + ((size_t)(3 * 16384) + (size_t)b * 1024) * 512;
  const bf16* A2 = QK + ((size_t)(4 * 16384) + (size_t)b * 1024) * 512;
  const bf16* A3 = QK + ((size_t)(5 * 16384) + (size_t)b * 1024) * 512;
  const bf16* Bt = W2T + (size_t)e * (256 * 2048);
  float* C = out + (size_t)e * (1024 * 256);
  gemm128p<float, 8>(A0, A1, A2, A3, 512, Bt, 2048, C, 256, bprp + m * 2048, 2048,
                     tm * 128, tn * 128);
}

// ---------- row L2-normalize (in place, bf16) + q_dot for Q tensors ----------
__global__ __launch_bounds__(256) void k_norm(
    bf16* __restrict__ QK, const float* __restrict__ wg, float* __restrict__ qdot)
{
  const int row = blockIdx.x * 4 + (threadIdx.x >> 6);
  const int lane = threadIdx.x & 63;
  bf16* p = QK + (size_t)row * 512 + lane * 8;
  short8 v = *(const short8*)p;
  float f[8];
  float ss = 0.f;
#pragma unroll
  for (int i = 0; i < 8; ++i) { f[i] = b2f(v[i]); ss += f[i] * f[i]; }
#pragma unroll
  for (int o = 32; o; o >>= 1) ss += __shfl_xor(ss, o);
  const float inv = 1.f / fmaxf(sqrtf(ss), 1e-12f);
  short8 ov;
#pragma unroll
  for (int i = 0; i < 8; ++i) ov[i] = (short)f2bu(f[i] * inv);
  *(short8*)p = ov;
  const int tt = row >> 14;
  if (tt < 3) {
    const float* wgm = wg + (size_t)tt * 512 + lane * 8;
    float dot = 0.f;
#pragma unroll
    for (int i = 0; i < 8; ++i) dot += f[i] * wgm[i];
    dot *= inv;
#pragma unroll
    for (int o = 32; o; o >>= 1) dot += __shfl_xor(dot, o);
    if (lane == 0) qdot[row] = dot;
  }
}

// ---------- gate ----------
__global__ __launch_bounds__(256) void k_G(
    const float* __restrict__ qdot, const bf16* __restrict__ QK, float* __restrict__ G)
{
  const int e = blockIdx.x;       // m*16+b
  const int m = e >> 4, b = e & 15;
  const int d0 = blockIdx.y << 6;
  __shared__ float Al[1024];
  __shared__ float red[4];
  __shared__ float Gp[4][64];
  const int t = threadIdx.x;
  const float* qd = qdot + (size_t)m * 16384 + (size_t)b * 1024;
  float ss = 0.f;
#pragma unroll
  for (int i = 0; i < 4; ++i) {
    float x = qd[t + i * 256] * SCALE_F;
    Al[t + i * 256] = x;
    ss += x * x;
  }
#pragma unroll
  for (int o = 32; o; o >>= 1) ss += __shfl_xor(ss, o);
  if ((t & 63) == 0) red[t >> 6] = ss;
  __syncthreads();
  const float inv = 1.f / fmaxf(sqrtf(red[0] + red[1] + red[2] + red[3]), 1e-12f);

  const int d = d0 + (t & 63);
  const int q = t >> 6;
  const bf16* Qb = QK + ((size_t)m * 16384 + (size_t)b * 1024) * 512 + d;
  float g = 0.f;
  for (int n = q * 256; n < q * 256 + 256; ++n)
    g += Al[n] * b2f(*(const short*)&Qb[(size_t)n * 512]);
  Gp[q][t & 63] = g;
  __syncthreads();
  if (t < 64)
    G[(size_t)e * 512 + d0 + t] = (Gp[0][t] + Gp[1][t] + Gp[2][t] + Gp[3][t]) * inv;
}

// ---------- W2T[m,b] [256][2048] bf16 ----------
__global__ __launch_bounds__(256) void k_w2t(
    const bf16* __restrict__ WfT, const float* __restrict__ WpfT,
    const float* __restrict__ G, bf16* __restrict__ W2T)
{
  const int e = blockIdx.x;
  const int m = e >> 4;
  const int fi = (m == 0) ? 0 : 1;
  const int t = threadIdx.x;
  bf16* out = W2T + (size_t)e * (256 * 2048);
  __shared__ float Gl[512];
  Gl[t] = G[(size_t)e * 512 + t];
  Gl[t + 256] = G[(size_t)e * 512 + t + 256];
  __syncthreads();
  const int k = t * 8;
  for (int nr = 0; nr < 16; ++nr) {
    const int n = blockIdx.y * 16 + nr;
    if (k < 512) {
      *(short8*)&out[(size_t)n * 2048 + k] =
          *(const short8*)&WfT[((size_t)fi * 256 + n) * 512 + k];
    } else {
      const int j = (k >> 9) - 1;
      const int d = k & 511;
      const float* src = WpfT + (((size_t)(m * 3 + j) * 256 + n) * 512 + d);
      short8 o;
#pragma unroll
      for (int i = 0; i < 8; ++i) o[i] = (short)f2bu(Gl[d + i] * src[i]);
      *(short8*)&out[(size_t)n * 2048 + k] = o;
    }
  }
}

// ---------- launch ----------
extern "C" void kernel_launch(void* const* d_in, const int* in_sizes, int n_in,
                              void* d_out, int out_size, void* d_ws, size_t ws_size,
                              hipStream_t stream) {
  const float* x_lv = (const float*)d_in[0];
  const float* x_myo = (const float*)d_in[1];
  const float* x_rv = (const float*)d_in[2];
  const float* Wq = (const float*)d_in[3];
  const float* bq = (const float*)d_in[4];
  const float* Wk = (const float*)d_in[5];
  const float* bk = (const float*)d_in[6];
  const float* wg = (const float*)d_in[7];
  const float* Wp = (const float*)d_in[8];
  const float* bp = (const float*)d_in[9];
  const float* Wf = (const float*)d_in[10];
  const float* bfv = (const float*)d_in[11];
  float* out = (float*)d_out;

  char* ws = (char*)d_ws;
  bf16* QK    = (bf16*)(ws);                      // 6*16384*512*2 = 100663296
  bf16* Xbf   = (bf16*)(ws + 100663296);          // 3*16384*512*2 = 50331648
  bf16* WT    = (bf16*)(ws + 150994944);          // 6*512*512*2   = 3145728
  bf16* Wpbf  = (bf16*)(ws + 154140672);          // 9*512*512*2   = 4718592
  bf16* WfT   = (bf16*)(ws + 158859264);          // 2*256*512*2   = 524288
  float* WpfT = (float*)(ws + 159383552);         // 9*256*512*4   = 4718592
  float* qdot = (float*)(ws + 164102144);         // 3*16384*4     = 196608
  float* G    = (float*)(ws + 164298752);         // 48*512*4      = 98304
  float* bprp = (float*)(ws + 164397056);         // 3*8*256*4     = 24576
  bf16* W2T   = Xbf;  // Xbf dead after GEMM1; W2T = 48*256*2048*2 = 50331648

  // fused prep: X convert + weight transposes/copies + bprime partials
  k_prep<<<25624, 256, 0, stream>>>(x_lv, x_myo, x_rv, Xbf, Wq, Wk, Wf, Wp,
                                    bp, bfv, WT, WfT, Wpbf, bprp);

  // projections (6 GEMMs of 16384x512x512) -> QK, 256^2 pipelined
  k_gemm1<<<768, 512, 0, stream>>>(Xbf, WT, bq, bk, QK);

  // normalize rows in place + q_dot
  k_norm<<<24576, 256, 0, stream>>>(QK, wg, qdot);

  // WpfT = Wf^T @ Wp^T (9 GEMMs of 256x512x512)
  k_gemm_wpf<<<dim3(8, 9), 256, 0, stream>>>(WfT, Wpbf, WpfT);

  // gate G per (m,b), 8 d-chunks
  k_G<<<dim3(48, 8), 256, 0, stream>>>(qdot, QK, G);

  // per-(m,b) stacked weights (reuses Xbf region)
  k_w2t<<<dim3(48, 16), 256, 0, stream>>>(WfT, WpfT, G, W2T);

  // final batched GEMM: 48 x (1024x256, K=2048) -> out, 128^2 pipelined, 2/CU
  k_gemm2<<<768, 256, 0, stream>>>(QK, W2T, bprp, out);
}